// Round 5
// baseline (2010.147 us; speedup 1.0000x reference)
//
#include <hip/hip_runtime.h>

// LogEig of 32768 SPD 32x32 fp32 matrices via one-sided Jacobi.
// 1 block = 1 wave = 2 matrices; lane owns one column (16 x float2 in VGPRs).
// Round-robin tournament pairing; norms recomputed fresh each round (carrying
// them (r2) destroys relative accuracy of small eigenvalues -> FAILED).
// SWEEPS=10 is REQUIRED: 8 sweeps leaves clustered-eigenvalue matrices
// unconverged (r2: absmax 1.59, r4: absmax 2.33 — both ran 8 sweeps; r1/r3 at
// 10 sweeps pass with 0.0195). Convergence tail is the accuracy limiter.
// r3 lesson: LLVM scalarizes v2f arithmetic (237 VALU instr/round measured via
// VALUBusy accounting) -> force v_pk_fma_f32/v_pk_mul_f32 with inline asm, and
// batch all bpermutes before the norm math so DS latency overlaps VALU work.

typedef float v2f __attribute__((ext_vector_type(2)));

#define SWEEPS 10

static __device__ __forceinline__ float bperm(int addr, float v) {
    return __builtin_bit_cast(float,
        __builtin_amdgcn_ds_bpermute(addr, __builtin_bit_cast(int, v)));
}

// Packed fp32 ops — LLVM does not form v_pk_*_f32 from ext-vector code on its
// own (r3 evidence: VALU instr count unchanged vs scalar r1).
static __device__ __forceinline__ v2f pk_fma(v2f a, v2f b, v2f c) {
    double r;
    asm("v_pk_fma_f32 %0, %1, %2, %3"
        : "=v"(r)
        : "v"(__builtin_bit_cast(double, a)),
          "v"(__builtin_bit_cast(double, b)),
          "v"(__builtin_bit_cast(double, c)));
    return __builtin_bit_cast(v2f, r);
}
static __device__ __forceinline__ v2f pk_mul(v2f a, v2f b) {
    double r;
    asm("v_pk_mul_f32 %0, %1, %2"
        : "=v"(r)
        : "v"(__builtin_bit_cast(double, a)),
          "v"(__builtin_bit_cast(double, b)));
    return __builtin_bit_cast(v2f, r);
}

__global__ __launch_bounds__(64, 4) void logeig_kernel(const float* __restrict__ P,
                                                       float* __restrict__ out,
                                                       int nmat) {
    const int lane = threadIdx.x;     // 0..63
    const int half = lane >> 5;       // which matrix in this wave
    const int c    = lane & 31;       // owned column index
    int mat = blockIdx.x * 2 + half;
    if (mat >= nmat) mat = nmat - 1;

    // Load column c (P symmetric -> column c == row c, contiguous).
    v2f w2[16];
    {
        const float4* src4 =
            reinterpret_cast<const float4*>(P + (size_t)mat * 1024 + (size_t)c * 32);
        #pragma unroll
        for (int k = 0; k < 8; ++k) {
            float4 v = src4[k];
            w2[2*k]   = (v2f){v.x, v.y};
            w2[2*k+1] = (v2f){v.z, v.w};
        }
    }

    const int laneb = lane << 2;

    #pragma unroll 1
    for (int sweep = 0; sweep < SWEEPS; ++sweep) {
        #pragma unroll 1
        for (int r = 0; r < 31; ++r) {
            // Tournament pairing: players 0..30 rotate, 31 fixed.
            int m = 2 * r - c;
            m = (m < 0)   ? m + 31 : m;
            m = (m >= 31) ? m - 31 : m;
            int o = m;
            if (c == r)  o = 31;
            if (c == 31) o = r;
            const int addr = laneb ^ ((c ^ o) << 2);  // partner byte-address

            // (1) Batch-issue all 32 partner-column bpermutes (independent).
            v2f o2[16];
            #pragma unroll
            for (int k = 0; k < 16; ++k) {
                o2[k][0] = bperm(addr, w2[k][0]);
                o2[k][1] = bperm(addr, w2[k][1]);
            }
            // (2) Own norm — independent of DS results, overlaps bperm flight.
            v2f nA = pk_mul(w2[0], w2[0]);
            v2f nB = pk_mul(w2[1], w2[1]);
            #pragma unroll
            for (int k = 2; k < 16; k += 2) {
                nA = pk_fma(w2[k],     w2[k],     nA);
                nB = pk_fma(w2[k + 1], w2[k + 1], nB);
            }
            const float nrm = (nA[0] + nA[1]) + (nB[0] + nB[1]);
            const float onrm = bperm(addr, nrm);   // queued after o2 (DS in-order)
            // (3) Dot — products commute, same summation order on both lanes
            //     of a pair -> bitwise-identical dot -> identical rotation.
            v2f dA = pk_mul(w2[0], o2[0]);
            v2f dB = pk_mul(w2[1], o2[1]);
            #pragma unroll
            for (int k = 2; k < 16; k += 2) {
                dA = pk_fma(w2[k],     o2[k],     dA);
                dB = pk_fma(w2[k + 1], o2[k + 1], dB);
            }
            const float dot = (dA[0] + dA[1]) + (dB[0] + dB[1]);

            const bool is_p = (c < o);
            const float gpp = is_p ? nrm : onrm;
            const float gqq = is_p ? onrm : nrm;

            // Jacobi rotation zeroing Gram(p,q); small-root t of t^2+2*tau*t-1=0.
            const float tau = (gqq - gpp) * 0.5f * __builtin_amdgcn_rcpf(dot);
            const float at  = fabsf(tau);
            float t = __builtin_amdgcn_rcpf(at + __builtin_amdgcn_sqrtf(fmaf(at, at, 1.f)));
            t = copysignf(t, tau);
            if (fabsf(dot) < 1e-37f) t = 0.f;   // skip / kill 0/0 NaN
            const float cr = __builtin_amdgcn_rsqf(fmaf(t, t, 1.f));
            const float sr = t * cr;
            const float se = is_p ? -sr : sr;   // p: w' = c*w - s*o ; q: w' = c*w + s*o

            const v2f cr2 = {cr, cr};
            const v2f se2 = {se, se};
            #pragma unroll
            for (int k = 0; k < 16; ++k)
                w2[k] = pk_fma(cr2, w2[k], pk_mul(se2, o2[k]));
        }
    }

    // ---- epilogue: sigma, log, normalize, X = sum_c l_c * u_c u_c^T ----
    v2f nA = pk_mul(w2[0], w2[0]);
    v2f nB = pk_mul(w2[1], w2[1]);
    #pragma unroll
    for (int k = 2; k < 16; k += 2) {
        nA = pk_fma(w2[k],     w2[k],     nA);
        nB = pk_fma(w2[k + 1], w2[k + 1], nB);
    }
    const float nrm2 = (nA[0] + nA[1]) + (nB[0] + nB[1]);
    const float inv = __builtin_amdgcn_rsqf(nrm2);               // 1/sigma
    const float lg  = 0.34657359f * __builtin_amdgcn_logf(nrm2); // ln(sigma)

    // LDS stride 36: per-lane strided reads conflict-free, rows 16B-aligned.
    __shared__ __align__(16) float S[2][32][36];
    __shared__ float L[2][32];
    #pragma unroll
    for (int k = 0; k < 16; ++k) {
        S[half][c][2*k]   = w2[k][0] * inv;
        S[half][c][2*k+1] = w2[k][1] * inv;
    }
    L[half][c] = lg;
    __syncthreads();

    // Lane computes row i of X: X[i][j] = sum_cc l*u[i]*u[j].
    const int i = c;
    v2f acc[16];
    #pragma unroll
    for (int j = 0; j < 16; ++j) acc[j] = (v2f){0.f, 0.f};
    #pragma unroll 4
    for (int cc = 0; cc < 32; ++cc) {
        const float si = S[half][cc][i];
        const float mm = si * L[half][cc];
        const v2f mm2 = {mm, mm};
        const float4* row4 = reinterpret_cast<const float4*>(&S[half][cc][0]);
        #pragma unroll
        for (int j4 = 0; j4 < 8; ++j4) {
            float4 v = row4[j4];
            acc[2*j4]   = pk_fma(mm2, (v2f){v.x, v.y}, acc[2*j4]);
            acc[2*j4+1] = pk_fma(mm2, (v2f){v.z, v.w}, acc[2*j4+1]);
        }
    }

    float4* dst4 = reinterpret_cast<float4*>(out + (size_t)mat * 1024 + (size_t)i * 32);
    #pragma unroll
    for (int j4 = 0; j4 < 8; ++j4) {
        dst4[j4] = make_float4(acc[2*j4][0], acc[2*j4][1], acc[2*j4+1][0], acc[2*j4+1][1]);
    }
}

extern "C" void kernel_launch(void* const* d_in, const int* in_sizes, int n_in,
                              void* d_out, int out_size, void* d_ws, size_t ws_size,
                              hipStream_t stream) {
    const float* P = (const float*)d_in[0];
    float* out = (float*)d_out;
    const int nmat = in_sizes[0] / 1024;     // 32768
    const int nblocks = (nmat + 1) / 2;      // 2 matrices per 64-thread block
    logeig_kernel<<<nblocks, 64, 0, stream>>>(P, out, nmat);
}